// Round 10
// baseline (302.774 us; speedup 1.0000x reference)
//
#include <hip/hip_runtime.h>

#define BATCH 1024
#define STSZ 16641
#define ATSZ 129
#define ST1SZ 16384
#define K1 33154
#define K1P 33280          // padded to 520 * 64
#define HID 512
#define ODIM 129
#define NKT 520            // K1P / 64
#define NSLICE 32
#define XGB (K1P / 8)      // 4160 groups of 8 cols per row
#define NPACKX (17 * 1024) // packX sub-grid: 17 col-blocks (17*256=4352 >= 4160) x 1024 rows
#define NPACKW (NKT * 8)   // packW1 sub-grid: 520 k-tiles x 8 n-tiles

typedef __bf16 bf16;
typedef bf16 bf16x8 __attribute__((ext_vector_type(8)));
typedef float floatx4 __attribute__((ext_vector_type(4)));
typedef float f32x4u __attribute__((ext_vector_type(4), aligned(4)));  // 4B-aligned vector load
typedef unsigned short ushort8v __attribute__((ext_vector_type(8)));

typedef __attribute__((address_space(3))) unsigned int as3_uint;
typedef __attribute__((address_space(1))) unsigned int as1_uint;

__device__ __forceinline__ unsigned short f2bf(float f) {
  unsigned int u = __float_as_uint(f);
  unsigned int r = (u + 0x7FFFu + ((u >> 16) & 1u)) >> 16;  // RNE
  return (unsigned short)r;
}
__device__ __forceinline__ float bf2f(unsigned short s) {
  unsigned int u = ((unsigned int)s) << 16;
  return __uint_as_float(u);
}

__device__ __forceinline__ void gload_lds16(const unsigned short* g, unsigned short* l) {
  __builtin_amdgcn_global_load_lds((const as1_uint*)g, (as3_uint*)l, 16, 0, 0);
}

// Load 8 consecutive fp32 from virtual concat(st, at, st1, pad) at [row, col..col+8).
// col is a multiple of 8; only 3 of 4160 groups straddle a boundary (element-wise path).
// (verified in rounds 1/4 — bit-identical to the 4-wide packX path)
__device__ __forceinline__ void loadA8(const float* __restrict__ st,
                                       const float* __restrict__ at,
                                       const float* __restrict__ st1,
                                       int row, int col, float f[8]) {
  if (col + 7 < STSZ) {
    const float* p = st + (long)row * STSZ + col;
    f32x4u a = *(const f32x4u*)p;
    f32x4u b = *(const f32x4u*)(p + 4);
    f[0] = a.x; f[1] = a.y; f[2] = a.z; f[3] = a.w;
    f[4] = b.x; f[5] = b.y; f[6] = b.z; f[7] = b.w;
  } else if (col >= STSZ + ATSZ && col + 7 < K1) {
    const float* p = st1 + (long)row * ST1SZ + (col - (STSZ + ATSZ));
    f32x4u a = *(const f32x4u*)p;
    f32x4u b = *(const f32x4u*)(p + 4);
    f[0] = a.x; f[1] = a.y; f[2] = a.z; f[3] = a.w;
    f[4] = b.x; f[5] = b.y; f[6] = b.z; f[7] = b.w;
  } else if (col >= STSZ && col + 7 < STSZ + ATSZ) {
    const float* p = at + (long)row * ATSZ + (col - STSZ);
    f32x4u a = *(const f32x4u*)p;
    f32x4u b = *(const f32x4u*)(p + 4);
    f[0] = a.x; f[1] = a.y; f[2] = a.z; f[3] = a.w;
    f[4] = b.x; f[5] = b.y; f[6] = b.z; f[7] = b.w;
  } else if (col >= K1) {
#pragma unroll
    for (int j = 0; j < 8; ++j) f[j] = 0.f;
  } else {
#pragma unroll
    for (int j = 0; j < 8; ++j) {
      int p = col + j;
      if (p < STSZ)               f[j] = st[(long)row * STSZ + p];
      else if (p < STSZ + ATSZ)   f[j] = at[(long)row * ATSZ + (p - STSZ)];
      else if (p < K1)            f[j] = st1[(long)row * ST1SZ + (p - (STSZ + ATSZ))];
      else                        f[j] = 0.f;
    }
  }
}

// ---------------- packAll: dispatch-merged packX (8-wide tiny blocks) + packW1 ----------------
// blocks [0, NPACKX): packX — one-shot blocks, 8 cols/thread (2x float4 load + ushort8 store)
// blocks [NPACKX, NPACKX+NPACKW): packW1 — W1 [K][N] fp32 -> transposed [N][K1P] bf16
__global__ __launch_bounds__(256) void packAll(const float* __restrict__ st,
                                               const float* __restrict__ at,
                                               const float* __restrict__ st1,
                                               const float* __restrict__ W1,
                                               unsigned short* __restrict__ Xb,
                                               unsigned short* __restrict__ W1t) {
  __shared__ unsigned short tile[64][68];   // packW1 branch only
  int bb  = blockIdx.x;
  int tid = threadIdx.x;

  if (bb < NPACKX) {
    // ---- packX: 8 cols/thread, one-shot tiny blocks (R5 shape, doubled width) ----
    int bx = bb % 17;               // compile-time-constant division (cheap magic-mul)
    int b  = bb / 17;
    int g  = bx * 256 + tid;        // group of 8 cols
    if (g >= XGB) return;
    int col = g * 8;
    float f[8];
    loadA8(st, at, st1, b, col, f);
    ushort8v o;
#pragma unroll
    for (int j = 0; j < 8; ++j) o[j] = f2bf(f[j]);
    *(ushort8v*)&Xb[(long)b * K1P + col] = o;
  } else {
    // ---- packW1 body (R9 verbatim; tile stride 68) ----
    int lb = bb - NPACKX;
    int k0 = (lb % NKT) * 64;
    int n0 = (lb / NKT) * 64;
    int nt = (tid & 15) * 4;      // n within tile, 0..60 step 4
    int kr = tid >> 4;            // 0..15
#pragma unroll
    for (int p = 0; p < 4; ++p) {
      int k = p * 16 + kr;
      int kk = k0 + k;
      float4 v = make_float4(0.f, 0.f, 0.f, 0.f);
      if (kk < K1) v = *(const float4*)&W1[(long)kk * HID + n0 + nt];
      unsigned short o[4] = { f2bf(v.x), f2bf(v.y), f2bf(v.z), f2bf(v.w) };
      *(ushort4*)&tile[k][nt] = *(const ushort4*)o;
    }
    __syncthreads();
    int kt = (tid & 15) * 4;      // k within tile, step 4
    int nr = tid >> 4;            // 0..15
#pragma unroll
    for (int p = 0; p < 4; ++p) {
      int n = p * 16 + nr;
      unsigned short o[4] = { tile[kt][n], tile[kt + 1][n], tile[kt + 2][n], tile[kt + 3][n] };
      *(ushort4*)&W1t[(long)(n0 + n) * K1P + k0 + kt] = *(const ushort4*)o;
    }
  }
}

// ---------------- GEMM1: Xb[1024,K1P] @ W1t[512,K1P]^T, split-K bf16 partials ----------------
// R9 verbatim: round-0 staging (pure global_load_lds), 128x128x64 tile,
// co-XCD decode, __launch_bounds__(256,4).
// LDS layout with XOR bank swizzle: chunk c holds rows c*8..c*8+7; lane stores
// global (row = c*8 + (lane>>3), colgrp = (lane&7)^(lane>>3)) at LDS lane*16B.
// Reader of (row, colgrp q): short idx = row*64 + 8*(q ^ (row&7)).
__global__ __launch_bounds__(256, 4) void gemm1(const unsigned short* __restrict__ Xb,
                                                const unsigned short* __restrict__ W1t,
                                                unsigned short* __restrict__ part) {
  __shared__ __align__(16) unsigned short lA[128 * 64];
  __shared__ __align__(16) unsigned short lB[128 * 64];

  // Co-XCD decode: HW round-robins blockIdx.x % 8 across XCDs.
  int hB  = blockIdx.x;               // 0..1023
  int xcd = hB & 7;
  int idx = hB >> 3;                  // 0..127
  int gidx = xcd * 32 + (idx >> 2);   // 0..255  (mt,s) group
  int nt = idx & 3;                   // 0..3 — the 4 A-sharers adjacent on one XCD
  int mt = gidx & 7;
  int s  = gidx >> 3;                 // 0..31
  int t0 = s * 16 + (s < 8 ? s : 8);  // ragged: 520 = 8*17 + 24*16
  int tc = 16 + (s < 8 ? 1 : 0);

  int tid = threadIdx.x;
  int wave = tid >> 6;
  int lane = tid & 63;
  int wm = (wave & 1) * 64;   // wave's M offset within tile
  int wn = (wave >> 1) * 64;  // wave's N offset within tile

  floatx4 acc[4][4] = {};

  const unsigned short* Ab = Xb  + (long)(mt * 128) * K1P;
  const unsigned short* Bb = W1t + (long)(nt * 128) * K1P;

  int srow = lane >> 3;                 // 0..7 within chunk
  int scol = ((lane & 7) ^ srow) * 8;   // swizzled col group, 0..56

  int sr = lane & 7;                    // (fragment row) & 7 — wave-uniform per lane

  for (int it = 0; it < tc; ++it) {
    long kOff = (long)(t0 + it) * 64;
#pragma unroll
    for (int r = 0; r < 4; ++r) {
      int c = wave * 4 + r;
      int row = c * 8 + srow;
      gload_lds16(Ab + (long)row * K1P + kOff + scol, &lA[c * 512 + lane * 8]);
      gload_lds16(Bb + (long)row * K1P + kOff + scol, &lB[c * 512 + lane * 8]);
    }
    __syncthreads();
#pragma unroll
    for (int ks = 0; ks < 2; ++ks) {
      int q = ks * 4 + (lane >> 4);               // col group 0..7
      int kidx = ((q ^ sr)) * 8;                  // swizzled short offset within row
      bf16x8 af[4], bfr[4];
#pragma unroll
      for (int i = 0; i < 4; ++i)
        af[i] = *(const bf16x8*)&lA[(wm + i * 16 + (lane & 15)) * 64 + kidx];
#pragma unroll
      for (int j = 0; j < 4; ++j)
        bfr[j] = *(const bf16x8*)&lB[(wn + j * 16 + (lane & 15)) * 64 + kidx];
#pragma unroll
      for (int i = 0; i < 4; ++i)
#pragma unroll
        for (int j = 0; j < 4; ++j)
          acc[i][j] = __builtin_amdgcn_mfma_f32_16x16x32_bf16(af[i], bfr[j], acc[i][j], 0, 0, 0);
    }
    __syncthreads();
  }

  // epilogue: C/D layout col=lane&15, row=(lane>>4)*4+reg ; bf16 partials
  unsigned short* P = part + (long)s * BATCH * HID;
  int cn = nt * 128 + wn + (lane & 15);
  int rbase = mt * 128 + wm + (lane >> 4) * 4;
#pragma unroll
  for (int i = 0; i < 4; ++i)
#pragma unroll
    for (int j = 0; j < 4; ++j)
#pragma unroll
      for (int r = 0; r < 4; ++r)
        P[(long)(rbase + i * 16 + r) * HID + cn + j * 16] = f2bf(acc[i][j][r]);
}

// ---------------- reduceGemm2: split-K reduce + bias + relu + h @ W2 + b2 (R9 verbatim) -------
// Block m: phase 1 reduces the 32 bf16 partial slices for row m (+b1, relu) into LDS hs[512];
// phase 2 computes out[m, 0..128] = hs @ W2 + b2 with 4 independent accumulator chains.
__global__ __launch_bounds__(256) void reduceGemm2(const unsigned short* __restrict__ part,
                                                   const float* __restrict__ b1,
                                                   const float* __restrict__ W2,
                                                   const float* __restrict__ b2,
                                                   float* __restrict__ out) {
  __shared__ float hs[HID];
  int m = blockIdx.x;
  int t = threadIdx.x;

  // phase 1: thread t owns columns n = 2t, 2t+1 (uint load = 2 bf16, coalesced)
  float2 bv = ((const float2*)b1)[t];
  float a0 = bv.x, a1 = bv.y;
#pragma unroll
  for (int s = 0; s < NSLICE; ++s) {
    unsigned int u = *(const unsigned int*)&part[((long)s * BATCH + m) * HID + 2 * t];
    a0 += bf2f((unsigned short)(u & 0xffffu));
    a1 += bf2f((unsigned short)(u >> 16));
  }
  hs[2 * t]     = fmaxf(a0, 0.f);
  hs[2 * t + 1] = fmaxf(a1, 0.f);
  __syncthreads();

  // phase 2: 129 threads, 4 independent FMA chains over k
  if (t < ODIM) {
    float c0 = 0.f, c1 = 0.f, c2 = 0.f, c3 = 0.f;
#pragma unroll 4
    for (int k = 0; k < HID; k += 4) {
      c0 += hs[k]     * W2[(long)(k)     * ODIM + t];
      c1 += hs[k + 1] * W2[(long)(k + 1) * ODIM + t];
      c2 += hs[k + 2] * W2[(long)(k + 2) * ODIM + t];
      c3 += hs[k + 3] * W2[(long)(k + 3) * ODIM + t];
    }
    out[(long)m * ODIM + t] = ((c0 + c1) + (c2 + c3)) + b2[t];
  }
}

extern "C" void kernel_launch(void* const* d_in, const int* in_sizes, int n_in,
                              void* d_out, int out_size, void* d_ws, size_t ws_size,
                              hipStream_t stream) {
  const float* st  = (const float*)d_in[0];
  const float* at  = (const float*)d_in[1];
  const float* st1 = (const float*)d_in[2];
  const float* W1  = (const float*)d_in[3];
  const float* b1  = (const float*)d_in[4];
  const float* W2  = (const float*)d_in[5];
  const float* b2  = (const float*)d_in[6];
  float* out = (float*)d_out;

  char* ws = (char*)d_ws;
  unsigned short* Xb   = (unsigned short*)ws;                                  // 68,157,440 B
  unsigned short* W1t  = (unsigned short*)(ws + (size_t)BATCH * K1P * 2);      // 34,078,720 B
  unsigned short* part = (unsigned short*)(ws + (size_t)BATCH * K1P * 2 + (size_t)HID * K1P * 2); // 33,554,432 B

  packAll<<<dim3(NPACKX + NPACKW), 256, 0, stream>>>(st, at, st1, W1, Xb, W1t);
  gemm1<<<dim3(1024), 256, 0, stream>>>(Xb, W1t, part);
  reduceGemm2<<<dim3(BATCH), 256, 0, stream>>>(part, b1, W2, b2, out);
}

// Round 12
// 297.868 us; speedup vs baseline: 1.0165x; 1.0165x over previous
//
#include <hip/hip_runtime.h>

#define BATCH 1024
#define STSZ 16641
#define ATSZ 129
#define ST1SZ 16384
#define K1 33154
#define K1P 33280          // padded to 520 * 64
#define HID 512
#define ODIM 129
#define NKT 520            // K1P / 64
#define NSLICE 32
#define NPACKX (33 * 1024) // packX sub-grid: 33 col-blocks x 1024 batch rows (verified best shape)
#define NPACKW (NKT * 8)   // packW1 sub-grid: 520 k-tiles x 8 n-tiles

typedef __bf16 bf16;
typedef bf16 bf16x8 __attribute__((ext_vector_type(8)));
typedef float floatx4 __attribute__((ext_vector_type(4)));
typedef float f32x4u __attribute__((ext_vector_type(4), aligned(4)));  // 4B-aligned vector load

typedef __attribute__((address_space(3))) unsigned int as3_uint;
typedef __attribute__((address_space(1))) unsigned int as1_uint;

__device__ __forceinline__ unsigned short f2bf(float f) {
  unsigned int u = __float_as_uint(f);
  unsigned int r = (u + 0x7FFFu + ((u >> 16) & 1u)) >> 16;  // RNE
  return (unsigned short)r;
}
__device__ __forceinline__ float bf2f(unsigned short s) {
  unsigned int u = ((unsigned int)s) << 16;
  return __uint_as_float(u);
}

__device__ __forceinline__ void gload_lds16(const unsigned short* g, unsigned short* l) {
  __builtin_amdgcn_global_load_lds((const as1_uint*)g, (as3_uint*)l, 16, 0, 0);
}

// ---------------- packAll: dispatch-merged packX + packW1 (verified 299.3 µs config) ----------
// blocks [0, NPACKX): packX — concat(st, at, st1) -> bf16 Xb, padded to K1P (4 cols/thread)
// blocks [NPACKX, NPACKX+NPACKW): packW1 — W1 [K][N] fp32 -> transposed [N][K1P] bf16
__global__ __launch_bounds__(256) void packAll(const float* __restrict__ st,
                                               const float* __restrict__ at,
                                               const float* __restrict__ st1,
                                               const float* __restrict__ W1,
                                               unsigned short* __restrict__ Xb,
                                               unsigned short* __restrict__ W1t) {
  __shared__ unsigned short tile[64][68];   // packW1 branch only; stride 68 => 4-way conflicts (was 8-way at 72)
  int bb  = blockIdx.x;
  int tid = threadIdx.x;

  if (bb < NPACKX) {
    // ---- packX body (tiny one-shot blocks, 4 cols/thread — empirically best of 4 shapes) ----
    int bx = bb % 33;
    int b  = bb / 33;
    int g  = bx * 256 + tid;        // group of 4 cols
    if (g >= K1P / 4) return;
    int col = g * 4;
    const float* srow  = st  + (long)b * STSZ;
    const float* arow  = at  + (long)b * ATSZ;
    const float* s1row = st1 + (long)b * ST1SZ;

    float4 v;
    if (col + 3 < STSZ) {
      f32x4u t = *(const f32x4u*)(srow + col);
      v = make_float4(t.x, t.y, t.z, t.w);
    } else if (col >= STSZ + ATSZ && col + 3 < K1) {
      f32x4u t = *(const f32x4u*)(s1row + (col - (STSZ + ATSZ)));
      v = make_float4(t.x, t.y, t.z, t.w);
    } else if (col >= STSZ && col + 3 < STSZ + ATSZ) {
      f32x4u t = *(const f32x4u*)(arow + (col - STSZ));
      v = make_float4(t.x, t.y, t.z, t.w);
    } else if (col >= K1) {
      v = make_float4(0.f, 0.f, 0.f, 0.f);
    } else {
      float e[4];
#pragma unroll
      for (int j = 0; j < 4; ++j) {
        int p = col + j;
        if (p < STSZ)                 e[j] = srow[p];
        else if (p < STSZ + ATSZ)     e[j] = arow[p - STSZ];
        else if (p < K1)              e[j] = s1row[p - (STSZ + ATSZ)];
        else                          e[j] = 0.f;
      }
      v = make_float4(e[0], e[1], e[2], e[3]);
    }
    unsigned short o[4] = { f2bf(v.x), f2bf(v.y), f2bf(v.z), f2bf(v.w) };
    *(ushort4*)&Xb[(long)b * K1P + col] = *(const ushort4*)o;
  } else {
    // ---- packW1 body (tile stride 68, verified bit-identical output) ----
    int lb = bb - NPACKX;
    int k0 = (lb % NKT) * 64;
    int n0 = (lb / NKT) * 64;
    int nt = (tid & 15) * 4;      // n within tile, 0..60 step 4
    int kr = tid >> 4;            // 0..15
#pragma unroll
    for (int p = 0; p < 4; ++p) {
      int k = p * 16 + kr;
      int kk = k0 + k;
      float4 v = make_float4(0.f, 0.f, 0.f, 0.f);
      if (kk < K1) v = *(const float4*)&W1[(long)kk * HID + n0 + nt];
      unsigned short o[4] = { f2bf(v.x), f2bf(v.y), f2bf(v.z), f2bf(v.w) };
      *(ushort4*)&tile[k][nt] = *(const ushort4*)o;
    }
    __syncthreads();
    int kt = (tid & 15) * 4;      // k within tile, step 4
    int nr = tid >> 4;            // 0..15
#pragma unroll
    for (int p = 0; p < 4; ++p) {
      int n = p * 16 + nr;
      unsigned short o[4] = { tile[kt][n], tile[kt + 1][n], tile[kt + 2][n], tile[kt + 3][n] };
      *(ushort4*)&W1t[(long)(n0 + n) * K1P + k0 + kt] = *(const ushort4*)o;
    }
  }
}

// ---------------- GEMM1: Xb[1024,K1P] @ W1t[512,K1P]^T, split-K bf16 partials ----------------
// Round-0 staging (pure global_load_lds), 128x128x64 tile, co-XCD decode, lb(256,4).
// LDS layout with XOR bank swizzle: chunk c holds rows c*8..c*8+7; lane stores
// global (row = c*8 + (lane>>3), colgrp = (lane&7)^(lane>>3)) at LDS lane*16B.
// Reader of (row, colgrp q): short idx = row*64 + 8*(q ^ (row&7)).
__global__ __launch_bounds__(256, 4) void gemm1(const unsigned short* __restrict__ Xb,
                                                const unsigned short* __restrict__ W1t,
                                                unsigned short* __restrict__ part) {
  __shared__ __align__(16) unsigned short lA[128 * 64];
  __shared__ __align__(16) unsigned short lB[128 * 64];

  // Co-XCD decode: HW round-robins blockIdx.x % 8 across XCDs.
  int hB  = blockIdx.x;               // 0..1023
  int xcd = hB & 7;
  int idx = hB >> 3;                  // 0..127
  int gidx = xcd * 32 + (idx >> 2);   // 0..255  (mt,s) group
  int nt = idx & 3;                   // 0..3 — the 4 A-sharers adjacent on one XCD
  int mt = gidx & 7;
  int s  = gidx >> 3;                 // 0..31
  int t0 = s * 16 + (s < 8 ? s : 8);  // ragged: 520 = 8*17 + 24*16
  int tc = 16 + (s < 8 ? 1 : 0);

  int tid = threadIdx.x;
  int wave = tid >> 6;
  int lane = tid & 63;
  int wm = (wave & 1) * 64;   // wave's M offset within tile
  int wn = (wave >> 1) * 64;  // wave's N offset within tile

  floatx4 acc[4][4] = {};

  const unsigned short* Ab = Xb  + (long)(mt * 128) * K1P;
  const unsigned short* Bb = W1t + (long)(nt * 128) * K1P;

  int srow = lane >> 3;                 // 0..7 within chunk
  int scol = ((lane & 7) ^ srow) * 8;   // swizzled col group, 0..56

  int sr = lane & 7;                    // (fragment row) & 7 — wave-uniform per lane

  for (int it = 0; it < tc; ++it) {
    long kOff = (long)(t0 + it) * 64;
#pragma unroll
    for (int r = 0; r < 4; ++r) {
      int c = wave * 4 + r;
      int row = c * 8 + srow;
      gload_lds16(Ab + (long)row * K1P + kOff + scol, &lA[c * 512 + lane * 8]);
      gload_lds16(Bb + (long)row * K1P + kOff + scol, &lB[c * 512 + lane * 8]);
    }
    __syncthreads();
#pragma unroll
    for (int ks = 0; ks < 2; ++ks) {
      int q = ks * 4 + (lane >> 4);               // col group 0..7
      int kidx = ((q ^ sr)) * 8;                  // swizzled short offset within row
      bf16x8 af[4], bfr[4];
#pragma unroll
      for (int i = 0; i < 4; ++i)
        af[i] = *(const bf16x8*)&lA[(wm + i * 16 + (lane & 15)) * 64 + kidx];
#pragma unroll
      for (int j = 0; j < 4; ++j)
        bfr[j] = *(const bf16x8*)&lB[(wn + j * 16 + (lane & 15)) * 64 + kidx];
#pragma unroll
      for (int i = 0; i < 4; ++i)
#pragma unroll
        for (int j = 0; j < 4; ++j)
          acc[i][j] = __builtin_amdgcn_mfma_f32_16x16x32_bf16(af[i], bfr[j], acc[i][j], 0, 0, 0);
    }
    __syncthreads();
  }

  // epilogue: C/D layout col=lane&15, row=(lane>>4)*4+reg ; bf16 partials
  unsigned short* P = part + (long)s * BATCH * HID;
  int cn = nt * 128 + wn + (lane & 15);
  int rbase = mt * 128 + wm + (lane >> 4) * 4;
#pragma unroll
  for (int i = 0; i < 4; ++i)
#pragma unroll
    for (int j = 0; j < 4; ++j)
#pragma unroll
      for (int r = 0; r < 4; ++r)
        P[(long)(rbase + i * 16 + r) * HID + cn + j * 16] = f2bf(acc[i][j][r]);
}

// ---------------- reduceGemm2: split-K reduce + bias + relu + h @ W2 + b2 ----------------
// Block m: phase 1 reduces the 32 bf16 partial slices for row m (+b1, relu) into LDS hs[512];
// phase 2 computes out[m, 0..128] = hs @ W2 + b2 with 4 independent accumulator chains.
__global__ __launch_bounds__(256) void reduceGemm2(const unsigned short* __restrict__ part,
                                                   const float* __restrict__ b1,
                                                   const float* __restrict__ W2,
                                                   const float* __restrict__ b2,
                                                   float* __restrict__ out) {
  __shared__ float hs[HID];
  int m = blockIdx.x;
  int t = threadIdx.x;

  // phase 1: thread t owns columns n = 2t, 2t+1 (uint load = 2 bf16, coalesced)
  float2 bv = ((const float2*)b1)[t];
  float a0 = bv.x, a1 = bv.y;
#pragma unroll
  for (int s = 0; s < NSLICE; ++s) {
    unsigned int u = *(const unsigned int*)&part[((long)s * BATCH + m) * HID + 2 * t];
    a0 += bf2f((unsigned short)(u & 0xffffu));
    a1 += bf2f((unsigned short)(u >> 16));
  }
  hs[2 * t]     = fmaxf(a0, 0.f);
  hs[2 * t + 1] = fmaxf(a1, 0.f);
  __syncthreads();

  // phase 2: 129 threads, 4 independent FMA chains over k
  if (t < ODIM) {
    float c0 = 0.f, c1 = 0.f, c2 = 0.f, c3 = 0.f;
#pragma unroll 4
    for (int k = 0; k < HID; k += 4) {
      c0 += hs[k]     * W2[(long)(k)     * ODIM + t];
      c1 += hs[k + 1] * W2[(long)(k + 1) * ODIM + t];
      c2 += hs[k + 2] * W2[(long)(k + 2) * ODIM + t];
      c3 += hs[k + 3] * W2[(long)(k + 3) * ODIM + t];
    }
    out[(long)m * ODIM + t] = ((c0 + c1) + (c2 + c3)) + b2[t];
  }
}

extern "C" void kernel_launch(void* const* d_in, const int* in_sizes, int n_in,
                              void* d_out, int out_size, void* d_ws, size_t ws_size,
                              hipStream_t stream) {
  const float* st  = (const float*)d_in[0];
  const float* at  = (const float*)d_in[1];
  const float* st1 = (const float*)d_in[2];
  const float* W1  = (const float*)d_in[3];
  const float* b1  = (const float*)d_in[4];
  const float* W2  = (const float*)d_in[5];
  const float* b2  = (const float*)d_in[6];
  float* out = (float*)d_out;

  char* ws = (char*)d_ws;
  unsigned short* Xb   = (unsigned short*)ws;                                  // 68,157,440 B
  unsigned short* W1t  = (unsigned short*)(ws + (size_t)BATCH * K1P * 2);      // 34,078,720 B
  unsigned short* part = (unsigned short*)(ws + (size_t)BATCH * K1P * 2 + (size_t)HID * K1P * 2); // 33,554,432 B

  packAll<<<dim3(NPACKX + NPACKW), 256, 0, stream>>>(st, at, st1, W1, Xb, W1t);
  gemm1<<<dim3(1024), 256, 0, stream>>>(Xb, W1t, part);
  reduceGemm2<<<dim3(BATCH), 256, 0, stream>>>(part, b1, W2, b2, out);
}